// Round 7
// baseline (328.534 us; speedup 1.0000x reference)
//
#include <hip/hip_runtime.h>
#include <math.h>

#define B_  2
#define T_  2048
#define C_  1024
#define H_  16
#define FC_ 5120   // 5*C

typedef __attribute__((ext_vector_type(8))) short  s16x8;
typedef __attribute__((ext_vector_type(4))) float  f32x4;
typedef __attribute__((ext_vector_type(2))) unsigned short u16x2;
typedef __attribute__((ext_vector_type(4))) unsigned short u16x4;
typedef __attribute__((ext_vector_type(8))) unsigned short u16x8;

#define AS1 __attribute__((address_space(1)))
#define AS3 __attribute__((address_space(3)))

__device__ __forceinline__ ushort f2bf(float f) {
    union { float f; unsigned u; } v; v.f = f;
    unsigned r = v.u + 0x7FFFu + ((v.u >> 16) & 1u);   // round-to-nearest-even
    return (ushort)(r >> 16);
}
__device__ __forceinline__ float bf2f(ushort u) {
    union { unsigned u; float f; } v; v.u = (unsigned)u << 16; return v.f;
}
// async global->LDS DMA, 16B per lane; LDS dest = wave-uniform base + lane*16
__device__ __forceinline__ void gload16(const void* g, void* l) {
    __builtin_amdgcn_global_load_lds((const AS1 unsigned int*)g,
                                     (AS3 unsigned int*)l, 16, 0, 0);
}

// ---------------- fused fp32 -> bf16 bulk convert for x + 4 weights ----------------
__global__ __launch_bounds__(256) void cvt_all_kernel(
        const float* __restrict__ x, const float* __restrict__ wq,
        const float* __restrict__ wg, const float* __restrict__ wp,
        const float* __restrict__ wf,
        ushort* __restrict__ xb, ushort* __restrict__ wqb, ushort* __restrict__ wgb,
        ushort* __restrict__ wpb, ushort* __restrict__ wfb) {
    int i = blockIdx.x * 256 + threadIdx.x;      // 8-elem chunk index, total 1703936
    const float* src; ushort* dst; int off;
    if (i < 524288)       { src = x;  dst = xb;  off = i; }
    else if (i < 1179648) { src = wq; dst = wqb; off = i - 524288; }
    else if (i < 1310720) { src = wg; dst = wgb; off = i - 1179648; }
    else if (i < 1441792) { src = wp; dst = wpb; off = i - 1310720; }
    else                  { src = wf; dst = wfb; off = i - 1441792; }
    float4 a = ((const float4*)src)[2*off];
    float4 b = ((const float4*)src)[2*off + 1];
    u16x8 o;
    o[0] = f2bf(a.x); o[1] = f2bf(a.y); o[2] = f2bf(a.z); o[3] = f2bf(a.w);
    o[4] = f2bf(b.x); o[5] = f2bf(b.y); o[6] = f2bf(b.z); o[7] = f2bf(b.w);
    *(u16x8*)(dst + 8*off) = o;
}

// ---------------- RMSNorm -> bf16 ----------------
__global__ __launch_bounds__(256) void rmsnorm_kernel(const float* __restrict__ x,
                                                      const float* __restrict__ rms_w,
                                                      ushort* __restrict__ xn) {
    int row = blockIdx.x;
    int tid = threadIdx.x;
    float4 v = ((const float4*)(x + (size_t)row * C_))[tid];
    float ss = v.x*v.x + v.y*v.y + v.z*v.z + v.w*v.w;
    #pragma unroll
    for (int m = 32; m >= 1; m >>= 1) ss += __shfl_xor(ss, m);
    __shared__ float wsum[4];
    if ((tid & 63) == 0) wsum[tid >> 6] = ss;
    __syncthreads();
    float tot = wsum[0] + wsum[1] + wsum[2] + wsum[3];
    float nrm = sqrtf(tot) * 0.03125f;
    float inv = 1.0f / fmaxf(nrm, 1e-8f);
    float4 w = ((const float4*)rms_w)[tid];
    u16x4 o;
    o[0] = f2bf(v.x * inv * w.x);  o[1] = f2bf(v.y * inv * w.y);
    o[2] = f2bf(v.z * inv * w.z);  o[3] = f2bf(v.w * inv * w.w);
    *(u16x4*)(xn + (size_t)row * C_ + 4*tid) = o;
}

// ---- xpos rotary + decay pre-scale on bf16 q,k:  qkvb[q|k] = rot(qk)*scales ----
__global__ __launch_bounds__(256) void xpos_bf16_kernel(const ushort* __restrict__ qktmp,
                                                        ushort* __restrict__ qkv) {
    int bt = blockIdx.x;
    int t = bt & (T_ - 1);
    float tf = (float)t;
    const ushort* row = qktmp + (size_t)bt * 2048;
    ushort* orow = qkv + (size_t)bt * 3072;
    float power = (tf - 1024.0f) * (1.0f / 512.0f);
    for (int i = threadIdx.x; i < 512; i += 256) {       // pair index, half=512
        float sv    = (2.0f * (float)i + 409.6f) * (1.0f / 1433.6f);
        float scale = exp2f(power * log2f(sv));
        float invf  = exp2f((float)i * (-13.287712379549449f / 512.0f));
        float ang   = tf * invf;
        float sn, cs;
        sincosf(ang, &sn, &cs);
        float rs = 1.0f / scale;
        int hh = i >> 5;                                  // head of this pair
        float lg2g = log2f(1.0f - exp2f(-5.0f - (float)hh));
        float gq = exp2f(lg2g * tf) * 0.125f;             // 0.125 * gamma^t
        float gk = exp2f(-lg2g * tf);                     // gamma^-t
        u16x2 qi = *(const u16x2*)(row + 2*i);
        u16x2 ki = *(const u16x2*)(row + 1024 + 2*i);
        float qx = bf2f(qi[0]), qy = bf2f(qi[1]);
        float kx = bf2f(ki[0]), ky = bf2f(ki[1]);
        float qox = (qx*(cs*scale) - qy*(sn*scale)) * gq;
        float qoy = (qy*(cs*scale) + qx*(sn*scale)) * gq;
        float kox = (kx*(cs*rs) - ky*(sn*rs)) * gk;
        float koy = (ky*(cs*rs) + kx*(sn*rs)) * gk;
        u16x2 qo; qo[0] = f2bf(qox); qo[1] = f2bf(qoy);
        u16x2 ko; ko[0] = f2bf(kox); ko[1] = f2bf(koy);
        *(u16x2*)(orow + 2*i) = qo;
        *(u16x2*)(orow + 1024 + 2*i) = ko;
    }
}

// ---------------- bf16 MFMA GEMM: C = A(MxK) @ W(NxK)^T ----------------
// Tile 128 x BN (BN=128 or 64), BK=64, 4 waves. Staging via global_load_lds width=16:
// LDS write is linear (base+lane*16), so the GLOBAL source address is pre-swizzled
// (lane l loads 16B slot (l&7)^(l>>3) of row 8c+(l>>3)); reads use byte^=(row&7)<<4.
// EPI: 0 plain fp32, 1 silu(acc+bias), 2 acc+bias+add1+add2,
//      3 qkvff routing: n<2048 -> oqk bf16; n<3072 -> ov bf16; else gelu -> offb bf16
template<int EPI, int BN>
__global__ __launch_bounds__(256) void gemm_bf16_kernel(
        const ushort* __restrict__ A, int lda,
        const ushort* __restrict__ W, int ldw,
        float* __restrict__ Cmat, int ldc, int K,
        const float* __restrict__ bias,
        const float* __restrict__ add1,
        const float* __restrict__ add2,
        ushort* __restrict__ oqk,
        ushort* __restrict__ ov,
        ushort* __restrict__ offb) {
    constexpr int NG = BN / 32;                 // n-frags per wave
    __shared__ __align__(16) ushort As[128*64];
    __shared__ __align__(16) ushort Bs[BN*64];
    int tid = threadIdx.x;
    int m0 = blockIdx.y * 128, n0 = blockIdx.x * BN;
    int wave = tid >> 6, lane = tid & 63;
    int lo = lane & 15, hi = lane >> 4;
    int wm = (wave >> 1) * 64, wn = (wave & 1) * (BN/2);
    int lrow  = lane >> 3;                      // row within 8-row chunk
    int gcol  = ((lane & 7) ^ lrow) * 8;        // pre-swizzled 16B slot (ushort offset)
    f32x4 acc[4][NG] = {};

    for (int k0 = 0; k0 < K; k0 += 64) {
        __syncthreads();                        // prev tile's LDS reads done
        #pragma unroll
        for (int i = 0; i < 4; ++i) {           // A: 16 chunks of 1KB, 4 per wave
            int c = wave*4 + i;
            gload16(A + (size_t)(m0 + c*8 + lrow) * lda + k0 + gcol,
                    (ushort*)As + c*512);
        }
        if constexpr (BN == 128) {
            #pragma unroll
            for (int i = 0; i < 4; ++i) {
                int c = wave*4 + i;
                gload16(W + (size_t)(n0 + c*8 + lrow) * ldw + k0 + gcol,
                        (ushort*)Bs + c*512);
            }
        } else {
            #pragma unroll
            for (int i = 0; i < 2; ++i) {       // B: 8 chunks, 2 per wave
                int c = wave*2 + i;
                gload16(W + (size_t)(n0 + c*8 + lrow) * ldw + k0 + gcol,
                        (ushort*)Bs + c*512);
            }
        }
        __syncthreads();                        // drains vmcnt(0): staging visible
        #pragma unroll
        for (int kc = 0; kc < 2; ++kc) {
            s16x8 af[4], bf[NG];
            #pragma unroll
            for (int g = 0; g < 4; ++g) {
                int arow = wm + g*16 + lo;
                af[g] = *(const s16x8*)((const char*)As +
                         arow*128 + ((kc*64 + hi*16) ^ ((arow & 7) << 4)));
            }
            #pragma unroll
            for (int g = 0; g < NG; ++g) {
                int brow = wn + g*16 + lo;
                bf[g] = *(const s16x8*)((const char*)Bs +
                         brow*128 + ((kc*64 + hi*16) ^ ((brow & 7) << 4)));
            }
            #pragma unroll
            for (int mg = 0; mg < 4; ++mg)
                #pragma unroll
                for (int ng = 0; ng < NG; ++ng)
                    acc[mg][ng] = __builtin_amdgcn_mfma_f32_16x16x32_bf16(
                        af[mg], bf[ng], acc[mg][ng], 0, 0, 0);
        }
    }
    #pragma unroll
    for (int mg = 0; mg < 4; ++mg) {
        #pragma unroll
        for (int r = 0; r < 4; ++r) {
            size_t m = (size_t)(m0 + wm + mg*16 + hi*4 + r);
            #pragma unroll
            for (int ng = 0; ng < NG; ++ng) {
                int n = n0 + wn + ng*16 + lo;
                float v = acc[mg][ng][r];
                if constexpr (EPI == 3) {
                    if (n0 < 2048)      oqk[m*2048 + n] = f2bf(v);
                    else if (n0 < 3072) ov[m*3072 + n] = f2bf(v);
                    else offb[m*2048 + (n - 3072)] =
                             f2bf(0.5f * v * (1.0f + erff(v * 0.70710678118f)));
                } else {
                    if (EPI == 1) {
                        float s = v + bias[n];
                        v = s / (1.0f + expf(-s));
                    } else if (EPI == 2) {
                        v += bias[n] + add1[m*ldc + n] + add2[m*ldc + n];
                    }
                    Cmat[m*ldc + n] = v;
                }
            }
        }
    }
}

// ---------------- retention attention, paired q-tiles (tt, 31-tt) ----------------
__global__ __launch_bounds__(256) void attn_mfma2_kernel(const ushort* __restrict__ qkv,
                                                         float* __restrict__ y) {
    __shared__ ushort Ks[2][64*64];
    __shared__ ushort Vt[2][64*64];
    __shared__ ushort Ss[4][16*64];
    int F = blockIdx.x;                     // 0..511
    int o = (F & 7) * 64 + (F >> 3);        // XCD grouping: o/64 == XCD (round-robin)
    int tta = o & 15;
    int h   = (o >> 4) & 15;
    int b   = o >> 8;
    int ttb = 31 - tta;
    int t0a = tta * 64, t0b = ttb * 64;
    int tid = threadIdx.x;
    int wave = tid >> 6, lane = tid & 63;
    int lo = lane & 15, hi = lane >> 4;
    const size_t bT = (size_t)b * T_;

    const ushort* qra = qkv + (bT + t0a + wave*16 + lo) * 3072 + h*64;
    const ushort* qrb = qkv + (bT + t0b + wave*16 + lo) * 3072 + h*64;
    s16x8 qa0 = *(const s16x8*)(qra + hi*8);
    s16x8 qa1 = *(const s16x8*)(qra + 32 + hi*8);
    s16x8 qb0 = *(const s16x8*)(qrb + hi*8);
    s16x8 qb1 = *(const s16x8*)(qrb + 32 + hi*8);
    f32x4 acca[4] = {}, accb[4] = {};

    int kr = tid >> 2, kc = tid & 3;                 // K staging
    int vd0 = (tid & 15) * 4, vs0 = (tid >> 4) * 4;  // V staging transpose
    u16x8 rka, rkb;
    u16x4 rv0, rv1, rv2, rv3;
    auto loadt = [&](int s0) {
        const ushort* src = qkv + (bT + s0 + kr) * 3072 + 1024 + h*64;
        rka = *(const u16x8*)(src + kc*8);
        rkb = *(const u16x8*)(src + (kc+4)*8);
        const ushort* vsrc = qkv + (bT + s0 + vs0) * 3072 + 2048 + h*64 + vd0;
        rv0 = *(const u16x4*)(vsrc);
        rv1 = *(const u16x4*)(vsrc + 3072);
        rv2 = *(const u16x4*)(vsrc + 2*3072);
        rv3 = *(const u16x4*)(vsrc + 3*3072);
    };
    int cur = 0;
    loadt(0);
    for (int st = 0; st <= ttb; ++st) {
        {   // write staged regs into LDS[cur]
            int base = kr * 128, sw = (kr & 7) << 4;
            *(u16x8*)((char*)Ks[cur] + ((base + kc*16) ^ sw))     = rka;
            *(u16x8*)((char*)Ks[cur] + ((base + (kc+4)*16) ^ sw)) = rkb;
            #pragma unroll
            for (int i = 0; i < 4; ++i) {
                u16x4 o4; o4[0] = rv0[i]; o4[1] = rv1[i]; o4[2] = rv2[i]; o4[3] = rv3[i];
                int d = vd0 + i;
                *(u16x4*)((char*)Vt[cur] + ((d*128 + vs0*2) ^ ((d & 7) << 4))) = o4;
            }
        }
        __syncthreads();
        if (st < ttb) loadt((st + 1) * 64);   // prefetch overlaps compute below

        auto compute = [&](s16x8 q0, s16x8 q1, f32x4* accy, bool diag) {
            f32x4 sacc[4] = {};
            #pragma unroll
            for (int sn = 0; sn < 4; ++sn) {
                int srow = sn*16 + lo;
                int rb2 = srow * 128, sw = (srow & 7) << 4;
                s16x8 kf0 = *(const s16x8*)((const char*)Ks[cur] + ((rb2 + hi*16) ^ sw));
                s16x8 kf1 = *(const s16x8*)((const char*)Ks[cur] + ((rb2 + 64 + hi*16) ^ sw));
                sacc[sn] = __builtin_amdgcn_mfma_f32_16x16x32_bf16(q0, kf0, sacc[sn], 0, 0, 0);
                sacc[sn] = __builtin_amdgcn_mfma_f32_16x16x32_bf16(q1, kf1, sacc[sn], 0, 0, 0);
            }
            #pragma unroll
            for (int sn = 0; sn < 4; ++sn) {
                int sl = sn*16 + lo;
                #pragma unroll
                for (int r = 0; r < 4; ++r) {
                    float v = sacc[sn][r];
                    if (diag && sl > wave*16 + hi*4 + r) v = 0.0f;
                    int tq = hi*4 + r;
                    *(ushort*)((char*)Ss[wave] + ((tq*128 + sl*2) ^ ((tq & 7) << 4))) = f2bf(v);
                }
            }
            s16x8 sa0 = *(const s16x8*)((const char*)Ss[wave] + ((lo*128 + hi*16) ^ ((lo & 7) << 4)));
            s16x8 sa1 = *(const s16x8*)((const char*)Ss[wave] + ((lo*128 + 64 + hi*16) ^ ((lo & 7) << 4)));
            #pragma unroll
            for (int dn = 0; dn < 4; ++dn) {
                int d = dn*16 + lo;
                int rb2 = d * 128, sw = (d & 7) << 4;
                s16x8 vf0 = *(const s16x8*)((const char*)Vt[cur] + ((rb2 + hi*16) ^ sw));
                s16x8 vf1 = *(const s16x8*)((const char*)Vt[cur] + ((rb2 + 64 + hi*16) ^ sw));
                accy[dn] = __builtin_amdgcn_mfma_f32_16x16x32_bf16(sa0, vf0, accy[dn], 0, 0, 0);
                accy[dn] = __builtin_amdgcn_mfma_f32_16x16x32_bf16(sa1, vf1, accy[dn], 0, 0, 0);
            }
        };
        compute(qb0, qb1, accb, st == ttb);          // B-tile: always active
        if (st <= tta) compute(qa0, qa1, acca, st == tta);
        cur ^= 1;
    }
    #pragma unroll
    for (int dn = 0; dn < 4; ++dn) {
        #pragma unroll
        for (int r = 0; r < 4; ++r) {
            int ta = t0a + wave*16 + hi*4 + r;
            int tb = t0b + wave*16 + hi*4 + r;
            y[(bT + ta) * C_ + h*64 + dn*16 + lo] = acca[dn][r];
            y[(bT + tb) * C_ + h*64 + dn*16 + lo] = accb[dn][r];
        }
    }
}

// ------- GroupNorm(per token, per head) * silu-gate -> bf16 ygated -------
__global__ __launch_bounds__(256) void gn_gate_kernel(const float* __restrict__ y,
                                                      const float* __restrict__ gate,
                                                      const float* __restrict__ gn_w,
                                                      const float* __restrict__ gn_b,
                                                      ushort* __restrict__ ygb) {
    int bt = blockIdx.x;
    int tid = threadIdx.x;
    float4 v = ((const float4*)(y + (size_t)bt * C_))[tid];
    float s1 = v.x + v.y + v.z + v.w;
    float s2 = v.x*v.x + v.y*v.y + v.z*v.z + v.w*v.w;
    #pragma unroll
    for (int m = 1; m < 16; m <<= 1) { s1 += __shfl_xor(s1, m); s2 += __shfl_xor(s2, m); }
    float mu   = s1 * (1.0f/64.0f);
    float var  = s2 * (1.0f/64.0f) - mu*mu;
    float rstd = rsqrtf(var + 1e-5f);
    float4 w  = ((const float4*)gn_w)[tid];
    float4 bb = ((const float4*)gn_b)[tid];
    float4 g  = ((const float4*)(gate + (size_t)bt * C_))[tid];
    u16x4 o;
    o[0] = f2bf(((v.x - mu)*rstd*w.x + bb.x) * g.x);
    o[1] = f2bf(((v.y - mu)*rstd*w.y + bb.y) * g.y);
    o[2] = f2bf(((v.z - mu)*rstd*w.z + bb.z) * g.z);
    o[3] = f2bf(((v.w - mu)*rstd*w.w + bb.w) * g.w);
    *(u16x4*)(ygb + (size_t)bt * C_ + 4*tid) = o;
}

extern "C" void kernel_launch(void* const* d_in, const int* in_sizes, int n_in,
                              void* d_out, int out_size, void* d_ws, size_t ws_size,
                              hipStream_t stream) {
    (void)in_sizes; (void)n_in; (void)out_size; (void)ws_size;
    const float* x       = (const float*)d_in[0];
    const float* w_qkvff = (const float*)d_in[1];
    const float* w_gated = (const float*)d_in[2];
    const float* b_gated = (const float*)d_in[3];
    const float* w_proj  = (const float*)d_in[4];
    const float* b_proj  = (const float*)d_in[5];
    const float* gn_w    = (const float*)d_in[6];
    const float* gn_b    = (const float*)d_in[7];
    const float* w_ff    = (const float*)d_in[8];
    const float* rms_w   = (const float*)d_in[9];
    float* out = (float*)d_out;

    const size_t NTOK = (size_t)B_ * T_;                  // 4096
    float* buf0   = (float*)d_ws;                         // ff_out fp32
    float* buf1   = buf0 + NTOK * C_;                     // y fp32
    float* buf2   = buf1 + NTOK * C_;                     // gate fp32
    ushort* qkvb  = (ushort*)(buf2 + NTOK * C_);          // 4096 x 3072 bf16 (q|k|v)
    ushort* qktmp = qkvb + NTOK * 3072;                   // 4096 x 2048 bf16 (pre-xpos q,k)
    ushort* xb    = qktmp + NTOK * 2048;                  // x bf16
    ushort* xnb   = xb + NTOK * C_;                       // rmsnorm(x) bf16
    ushort* ffb   = xnb + NTOK * C_;                      // gelu(ff) bf16 (4096x2048)
    ushort* ygb   = ffb + NTOK * 2048;                    // ygated bf16
    ushort* wqb   = ygb + NTOK * C_;                      // w_qkvff bf16 (5120x1024)
    ushort* wgb   = wqb + (size_t)FC_ * C_;               // w_gated bf16
    ushort* wpb   = wgb + (size_t)C_ * C_;                // w_proj bf16
    ushort* wfb   = wpb + (size_t)C_ * C_;                // w_ff bf16 (1024x2048)

    // fused bf16 conversions (x + all weights), 1703936 8-elem chunks
    cvt_all_kernel<<<6656, 256, 0, stream>>>(x, w_qkvff, w_gated, w_proj, w_ff,
                                             xb, wqb, wgb, wpb, wfb);
    rmsnorm_kernel<<<4096, 256, 0, stream>>>(x, rms_w, xnb);
    // qkvff GEMM with routed bf16 epilogue: q,k -> qktmp; v -> qkvb; gelu(ff) -> ffb
    gemm_bf16_kernel<3,128><<<dim3(40, 32), 256, 0, stream>>>(
        xnb, C_, wqb, C_, nullptr, 0, C_, nullptr, nullptr, nullptr, qktmp, qkvb, ffb);
    // xpos + decay prescale on q,k
    xpos_bf16_kernel<<<4096, 256, 0, stream>>>(qktmp, qkvb);
    // retention attention (paired tiles) -> y fp32
    attn_mfma2_kernel<<<512, 256, 0, stream>>>(qkvb, buf1);
    // gate = silu(x @ w_gated^T + b_gated) -> fp32
    gemm_bf16_kernel<1,64><<<dim3(16, 32), 256, 0, stream>>>(
        xb, C_, wgb, C_, buf2, C_, C_, b_gated, nullptr, nullptr, nullptr, nullptr, nullptr);
    // ygated = gate * (GN(y)*gn_w + gn_b) -> bf16
    gn_gate_kernel<<<4096, 256, 0, stream>>>(buf1, buf2, gn_w, gn_b, ygb);
    // ff_out = gelu(ff) @ w_ff^T  (K=2048) -> fp32
    gemm_bf16_kernel<0,64><<<dim3(16, 32), 256, 0, stream>>>(
        ffb, 2*C_, wfb, 2*C_, buf0, C_, 2*C_, nullptr, nullptr, nullptr, nullptr, nullptr, nullptr);
    // out = x + ff_out + (ygated @ w_proj^T + b_proj)
    gemm_bf16_kernel<2,64><<<dim3(16, 32), 256, 0, stream>>>(
        ygb, C_, wpb, C_, out, C_, C_, b_proj, x, buf0, nullptr, nullptr, nullptr);
}